// Round 3
// baseline (1524.013 us; speedup 1.0000x reference)
//
#include <hip/hip_runtime.h>
#include <stdint.h>

// SelfRNN: 4-layer tanh RNN, SEQ=256, B=64, H=512.
// R5: tag-signaled data exchange. R4 regressed (927->1035us): 32 serialized
// MALL RMWs per flag + 512 polling waves on 16 flag lines. Root fix: remove
// the flag protocol from the critical edge entirely. Each communicated h
// element is a packed dword (bf16<<16 | step_tag): producers fire-and-forget
// coherent dword stores (no drain, no RMW, no publish); consumers spin-load
// the DATA and check tags -> the h edge costs exactly one store->MALL->load
// round trip. No flags, no prep kernel, ONE dispatch.
//   - hsig ring: NBUF=8 step slots x [NL][BB][HH] packed dwords (4MB ws).
//     Tag t+1 disambiguates ring reuse AND the 0xAA ws poison (0xAAAA != any
//     valid tag; any stale tag != current -> treated as not-ready).
//   - Self-edge ring safety is hard-ordered (sibling reads complete >=2 steps
//     before overwrite). Feed-edge gets explicit backpressure: consumer waves
//     store per-wave progress; producer gates stores on min >= t-NBUF+1 (only
//     for t>=NBUF; check overlapped, ~never blocking). Correctness never
//     depends on dispatch timing.
//   - Own-column shortcut: a WG's own 128 h-cols go straight from registers
//     into the NEXT step's LDS buffer (bit-identical bf16) -> wait set is 3
//     foreign WGs, and 25% less coherent traffic.
//   - Fallback (ws too small): hsig = the states output region indexed by t
//     (no ring -> no backpressure), then rnn_fix converts packed->f32.

#define SEQ 256
#define BB  64
#define HH  512
#define NL  4
#define GM  4          // batch groups of 16 rows
#define GN  4          // column groups of 128 cols (16 per wave, 8 waves)
#define TPB 512        // threads per workgroup (8 waves)
#define NBUF 8         // h ring depth (power of 2)
#define PROG_SLOTS 32  // feed-consumer waves per (i,m): GN WGs x 8 waves
#define LDS_STRIDE 1032  // 1024 + 8 shorts pad -> conflict-benign b128 reads

typedef __attribute__((ext_vector_type(8))) short bf16x8;
typedef __attribute__((ext_vector_type(4))) float f32x4;

__device__ inline short f2bf(float f){
  uint32_t u = __builtin_bit_cast(uint32_t, f);
  u += 0x7fffu + ((u >> 16) & 1u);   // round-to-nearest-even
  return (short)(u >> 16);
}

__device__ inline float fast_tanh(float xv){
  xv = fminf(15.0f, fmaxf(-15.0f, xv));
  float e = __expf(2.0f * xv);
  return (e - 1.0f) / (e + 1.0f);
}

// Agent-coherent load of 8 packed dwords (4x u64 atomic: 8B atomicity covers
// the 4B tag+payload granule; no cross-word tearing concern).
__device__ inline void load_pk8(const uint32_t* p, uint32_t w[8]){
  const uint64_t* q = (const uint64_t*)p;
#pragma unroll
  for (int z = 0; z < 4; ++z){
    uint64_t u = __hip_atomic_load(q + z, __ATOMIC_RELAXED, __HIP_MEMORY_SCOPE_AGENT);
    w[2*z]   = (uint32_t)u;
    w[2*z+1] = (uint32_t)(u >> 32);
  }
}

// Spin until both 8-dword segments carry `tag`. Per-wave convergence (__all);
// inactive lanes (own-column shortcut) report ok. ~1 iteration in steady state.
__device__ inline void tag_load2(const uint32_t* s0, const uint32_t* s1,
                                 uint32_t tag, uint32_t wa[8], uint32_t wb[8],
                                 bool active){
  int it = 0; bool ok;
  do {
    ok = true;
    if (active){
      load_pk8(s0, wa); load_pk8(s1, wb);
#pragma unroll
      for (int j = 0; j < 8; ++j)
        ok = ok && ((wa[j] & 0xffffu) == tag) && ((wb[j] & 0xffffu) == tag);
    }
    if (++it > (1 << 20)) break;   // bailout: wrong-but-terminating beats hang
  } while (!__all(ok));
}

__device__ inline bf16x8 hi16x8(const uint32_t w[8]){
  bf16x8 s;
#pragma unroll
  for (int j = 0; j < 8; ++j) s[j] = (short)(w[j] >> 16);
  return s;
}

__device__ inline long hslot(int t, int i, int ring){
  long tt = ring ? (long)(t & (NBUF-1)) : (long)t;
  return (tt * NL + i) * (long)(BB*HH);
}

__global__ __launch_bounds__(TPB, 2)   // 2 waves/SIMD -> VGPR cap 256
void rnn_main(const float* __restrict__ x,
              const float* __restrict__ w_ih, const float* __restrict__ b_ih,
              const float* __restrict__ w_hh, const float* __restrict__ b_hh,
              float* __restrict__ out,
              uint32_t* __restrict__ hsig, int* __restrict__ prog, int ring)
{
  const int tid  = threadIdx.x;
  const int wv   = tid >> 6;             // 0..7
  const int lane = tid & 63;
  const int bid  = blockIdx.x;           // grid = NL*GM*GN = 64
  const int n = bid >> 4;                // 0..3 column group
  const int i = (bid >> 2) & 3;          // layer
  const int m = bid & 3;                 // batch group

  const int l15  = lane & 15;
  const int lq   = lane >> 4;            // quarter-wave 0..3
  const int jcol = n*128 + wv*16 + l15;  // this wave's 16 output cols
  const int ksub = lq * 8;

  // staging geometry: thread owns cols c0..c0+7 of rows r0 and r0+8
  const int r0 = tid >> 6;               // 0..7
  const int c0 = (tid & 63) * 8;         // 0..504
  const bool ownh = ((c0 >> 7) == n);    // this h-chunk is produced by our WG

  // Double-buffered A tile [16 rows][1024 k] bf16, padded. 2 x 33 KB = 66 KB.
  __shared__ short lA[2][16 * LDS_STRIDE];

  // ---- persistent weight fragments: B-operand, [16 cols x 1024 k] per wave ----
  bf16x8 wf[32];
  {
    const float* wih = w_ih + (long)i*HH*HH + (long)jcol*HH;
    const float* whh = w_hh + (long)i*HH*HH + (long)jcol*HH;
    #pragma unroll
    for (int kk = 0; kk < 16; ++kk){
      const float* p = wih + kk*32 + ksub;
      f32x4 a = *(const f32x4*)p, b = *(const f32x4*)(p + 4);
      bf16x8 s;
      s[0]=f2bf(a[0]); s[1]=f2bf(a[1]); s[2]=f2bf(a[2]); s[3]=f2bf(a[3]);
      s[4]=f2bf(b[0]); s[5]=f2bf(b[1]); s[6]=f2bf(b[2]); s[7]=f2bf(b[3]);
      wf[kk] = s;
      const float* q = whh + kk*32 + ksub;
      f32x4 c = *(const f32x4*)q, d = *(const f32x4*)(q + 4);
      bf16x8 u;
      u[0]=f2bf(c[0]); u[1]=f2bf(c[1]); u[2]=f2bf(c[2]); u[3]=f2bf(c[3]);
      u[4]=f2bf(d[0]); u[5]=f2bf(d[1]); u[6]=f2bf(d[2]); u[7]=f2bf(d[3]);
      wf[kk + 16] = u;
    }
  }
  const float bsum = b_ih[(long)i*HH + jcol] + b_hh[(long)i*HH + jcol];

  float* states = out + (long)SEQ*BB*HH;   // all_states region: [(t*4+i)][b][h]
  const int bg0 = m * 16;

  for (int t = 0; t < SEQ; ++t){
    short* buf  = lA[t & 1];
    short* bufN = lA[(t + 1) & 1];

    // ---- backpressure early-load (overlaps the h wait; check is later) ----
    const bool bp = (ring != 0) && (i < NL-1) && (t >= NBUF);
    int prg = 0x7fffffff;
    if (bp && lane < PROG_SLOTS)
      prg = __hip_atomic_load(&prog[((i+1)*GM + m)*PROG_SLOTS + lane],
                              __ATOMIC_RELAXED, __HIP_MEMORY_SCOPE_AGENT);

    // ---- h half (self edge, available earliest): spin on tagged data ----
    if (t > 0){
      const uint32_t* hb = hsig + hslot(t-1, i, ring);
      const uint32_t* s0 = hb + (long)(bg0 + r0    )*HH + c0;
      const uint32_t* s1 = hb + (long)(bg0 + r0 + 8)*HH + c0;
      uint32_t wa[8], wb[8];
      tag_load2(s0, s1, (uint32_t)t, wa, wb, !ownh);
      if (!ownh){
        *(bf16x8*)(buf + r0*LDS_STRIDE + 512 + c0)     = hi16x8(wa);
        *(bf16x8*)(buf + (r0+8)*LDS_STRIDE + 512 + c0) = hi16x8(wb);
      }
    }

    // ---- feed half ----
    if (i == 0){
      const float* xs0 = x + ((long)t*BB + bg0 + r0    )*HH + c0;
      const float* xs1 = x + ((long)t*BB + bg0 + r0 + 8)*HH + c0;
      f32x4 a = *(const f32x4*)xs0, b = *(const f32x4*)(xs0 + 4);
      f32x4 c = *(const f32x4*)xs1, d = *(const f32x4*)(xs1 + 4);
      bf16x8 s, u;
      s[0]=f2bf(a[0]); s[1]=f2bf(a[1]); s[2]=f2bf(a[2]); s[3]=f2bf(a[3]);
      s[4]=f2bf(b[0]); s[5]=f2bf(b[1]); s[6]=f2bf(b[2]); s[7]=f2bf(b[3]);
      u[0]=f2bf(c[0]); u[1]=f2bf(c[1]); u[2]=f2bf(c[2]); u[3]=f2bf(c[3]);
      u[4]=f2bf(d[0]); u[5]=f2bf(d[1]); u[6]=f2bf(d[2]); u[7]=f2bf(d[3]);
      *(bf16x8*)(buf + r0*LDS_STRIDE + c0)     = s;
      *(bf16x8*)(buf + (r0+8)*LDS_STRIDE + c0) = u;
    } else {
      const uint32_t* fb = hsig + hslot(t, i-1, ring);
      const uint32_t* s0 = fb + (long)(bg0 + r0    )*HH + c0;
      const uint32_t* s1 = fb + (long)(bg0 + r0 + 8)*HH + c0;
      uint32_t wa[8], wb[8];
      tag_load2(s0, s1, (uint32_t)(t + 1), wa, wb, true);
      *(bf16x8*)(buf + r0*LDS_STRIDE + c0)     = hi16x8(wa);
      *(bf16x8*)(buf + (r0+8)*LDS_STRIDE + c0) = hi16x8(wb);
      // publish feed progress: this wave's reads of h_{i-1}^t are complete.
      if (ring && lane == 0)
        __hip_atomic_store(&prog[(i*GM + m)*PROG_SLOTS + n*8 + wv], t + 1,
                           __ATOMIC_RELAXED, __HIP_MEMORY_SCOPE_AGENT);
    }
    __syncthreads();   // the ONE barrier of the step: stage -> MFMA-read

    // ---- MFMA: out[16 rows x 16 cols]/wave, K=1024 (512 at t==0) ----
    f32x4 acc = {0.f, 0.f, 0.f, 0.f};
    const short* arow = buf + l15*LDS_STRIDE + ksub;
    #pragma unroll
    for (int kk = 0; kk < 16; ++kk)
      acc = __builtin_amdgcn_mfma_f32_16x16x32_bf16(*(const bf16x8*)(arow + kk*32), wf[kk], acc, 0, 0, 0);
    if (t > 0){
      #pragma unroll
      for (int kk = 16; kk < 32; ++kk)
        acc = __builtin_amdgcn_mfma_f32_16x16x32_bf16(*(const bf16x8*)(arow + kk*32), wf[kk], acc, 0, 0, 0);
    }

    // ---- epilogue ----
    float vv[4]; short hb16[4];
    #pragma unroll
    for (int r = 0; r < 4; ++r){
      vv[r]  = fast_tanh(acc[r] + bsum);  // C/D: col=lane&15, row=lq*4+r
      hb16[r] = f2bf(vv[r]);
      // own-column shortcut: next step's h for OUR 128 cols goes straight to
      // the next LDS buffer (bit-identical to the hsig value). Safe: all waves
      // are past barrier t, so bufN's previous readers (step t-1) are done.
      if (t + 1 < SEQ)
        bufN[(lq*4 + r)*LDS_STRIDE + 512 + n*128 + wv*16 + l15] = hb16[r];
    }

    // ---- feed backpressure gate (only t>=NBUF; almost never blocks) ----
    if (bp){
      const int thr = t - NBUF + 1;
      bool okp = (lane >= PROG_SLOTS) || (prg >= thr);
      int itp = 0;
      while (!__all(okp)){
        __builtin_amdgcn_s_sleep(1);
        if (lane < PROG_SLOTS)
          prg = __hip_atomic_load(&prog[((i+1)*GM + m)*PROG_SLOTS + lane],
                                  __ATOMIC_RELAXED, __HIP_MEMORY_SCOPE_AGENT);
        okp = (lane >= PROG_SLOTS) || (prg >= thr);
        if (++itp > (1 << 20)) break;
      }
    }

    // ---- tagged h stores: fire-and-forget coherent dwords (no drain!) ----
    {
      uint32_t* hw = hsig + hslot(t, i, ring);
      const uint32_t tagv = (uint32_t)(t + 1);
      #pragma unroll
      for (int r = 0; r < 4; ++r){
        uint32_t pk = ((uint32_t)(uint16_t)hb16[r] << 16) | tagv;
        __hip_atomic_store(hw + (long)(bg0 + lq*4 + r)*HH + jcol, pk,
                           __ATOMIC_RELAXED, __HIP_MEMORY_SCOPE_AGENT);
      }
    }

    // ---- f32 result stores (not consumed in-kernel; drain in next step's
    //      shadow). In fallback mode states IS the comm buffer -> skip. ----
    if (ring){
      #pragma unroll
      for (int r = 0; r < 4; ++r){
        long srow = (long)(t*NL + i)*BB + bg0 + lq*4 + r;
        __builtin_nontemporal_store(vv[r], states + srow*HH + jcol);
      }
    }
    if (i == NL-1){
      #pragma unroll
      for (int r = 0; r < 4; ++r)
        __builtin_nontemporal_store(vv[r], out + ((long)t*BB + bg0 + lq*4 + r)*HH + jcol);
    }
  }
}

// Fallback-only pass: states region holds packed (bf16<<16|tag) words;
// convert in place to f32 (bf16 bits ARE the f32 high half).
__global__ void rnn_fix(uint32_t* __restrict__ s){
  long idx = ((long)blockIdx.x * TPB + threadIdx.x) * 8;
  uint32_t w[8];
  *(f32x4*)&w[0] = *(const f32x4*)(s + idx);
  *(f32x4*)&w[4] = *(const f32x4*)(s + idx + 4);
  #pragma unroll
  for (int j = 0; j < 8; ++j) w[j] &= 0xffff0000u;
  *(f32x4*)(s + idx)     = *(const f32x4*)&w[0];
  *(f32x4*)(s + idx + 4) = *(const f32x4*)&w[4];
}

extern "C" void kernel_launch(void* const* d_in, const int* in_sizes, int n_in,
                              void* d_out, int out_size, void* d_ws, size_t ws_size,
                              hipStream_t stream)
{
  (void)in_sizes; (void)n_in; (void)out_size;
  const float* x    = (const float*)d_in[0];
  const float* w_ih = (const float*)d_in[1];
  const float* b_ih = (const float*)d_in[2];
  const float* w_hh = (const float*)d_in[3];
  const float* b_hh = (const float*)d_in[4];
  float* out    = (float*)d_out;
  float* states = out + (long)SEQ*BB*HH;

  const size_t HS_BYTES   = (size_t)NBUF*NL*BB*HH*4;       // 4 MB ring
  const size_t PROG_BYTES = (size_t)NL*GM*PROG_SLOTS*4;    // 2 KB
  int ring = (d_ws != nullptr && ws_size >= HS_BYTES + PROG_BYTES) ? 1 : 0;

  uint32_t* hsig = ring ? (uint32_t*)d_ws : (uint32_t*)states;
  int*      prog = ring ? (int*)((char*)d_ws + HS_BYTES) : (int*)d_out; // unused if !ring

  hipLaunchKernelGGL(rnn_main, dim3(NL*GM*GN), dim3(TPB), 0, stream,
                     x, w_ih, b_ih, w_hh, b_hh, out, hsig, prog, ring);
  if (!ring){
    const long total = (long)SEQ*NL*BB*HH;                 // 33,554,432 words
    hipLaunchKernelGGL(rnn_fix, dim3((unsigned)(total/(TPB*8))), dim3(TPB), 0,
                       stream, (uint32_t*)states);
  }
}

// Round 4
// 1491.464 us; speedup vs baseline: 1.0218x; 1.0218x over previous
//
#include <hip/hip_runtime.h>
#include <stdint.h>

// SelfRNN: 4-layer tanh RNN, SEQ=256, B=64, H=512.
// R6: sentinel-tag protocol. Lessons: R3 (WG flags + barriers) = 927us best;
// R4 regressed via 32 serialized flag-RMWs; R5 regressed via tag-in-data spin
// BANDWIDTH (64B/lane/iter agent loads -> FETCH doubled, MALL congested).
// R6 combines the fixes:
//   - publish = per-wave PLAIN tag store (32 distinct dwords per (i,m) family,
//     one 128B line) after a per-wave vmcnt(0) drain of its own 4x2B act
//     stores. No RMW, no serialization, no drain-of-other-waves barrier.
//   - consume = combined spin: lanes 0-31 watch the self-family tag line
//     (need >= t), lanes 32-63 watch the feed-family line (need >= t+1).
//     2 coalesced 128B line loads per wave per iteration -> 16x less spin
//     traffic than R5, and the feed wait overlaps the self wait.
//   - tags self-initialize: ws is re-poisoned 0xAA each call -> tags read as
//     NEGATIVE ints -> signed compare (v >= target>0) sees unready. No prep
//     kernel, ONE dispatch. Fallback (no/small ws): __device__ globals +
//     epoch-bumped tag base (tiny bump kernel), same code path.
//   - comm payload = plain bf16 ring [NBUF=16][NL][BB][HH] (4MB). Freshness is
//     guaranteed by tag-after-drain; ring reuse is safe because family WGs are
//     lockstep within 1 step and feed skew << NBUF (no backpressure needed).
//   - keeps R3 geometry: GN=4, 8 waves, double-buffered LDS A-tile, ONE
//     stage->MFMA barrier per step; R5's own-column shortcut (own 128 h-cols
//     register->next LDS buffer; wait set = 3 foreign WGs); f32 result stores
//     deferred past the tag publish.

#define SEQ 256
#define BB  64
#define HH  512
#define NL  4
#define GM  4          // batch groups of 16 rows
#define GN  4          // column groups of 128 cols (16 per wave, 8 waves)
#define TPB 512        // threads per workgroup (8 waves)
#define NBUF 16        // h ring depth (power of 2)
#define LDS_STRIDE 1032  // 1024 + 8 shorts pad -> conflict-benign b128 reads
#define NTAG (NL*GM*32)  // 32 producer waves per (i,m) family

typedef __attribute__((ext_vector_type(8))) short bf16x8;
typedef __attribute__((ext_vector_type(4))) float f32x4;

// Fallback comm buffers (used only when ws is absent/small). Tag base is
// epoch*512 so stale tags from previous calls never satisfy current targets.
__device__ short g_hring_fb[(size_t)NBUF*NL*BB*HH];  // 4 MB
__device__ int   g_tags_fb[NTAG];
__device__ int   g_epoch = 0;

__global__ void bump_epoch(){ g_epoch += 1; }

__device__ inline short f2bf(float f){
  uint32_t u = __builtin_bit_cast(uint32_t, f);
  u += 0x7fffu + ((u >> 16) & 1u);   // round-to-nearest-even
  return (short)(u >> 16);
}

__device__ inline float fast_tanh(float xv){
  xv = fminf(15.0f, fmaxf(-15.0f, xv));
  float e = __expf(2.0f * xv);
  return (e - 1.0f) / (e + 1.0f);
}

// Agent-coherent 16B load (2x u64; bypasses stale L1/L2 lines on ring reuse).
__device__ inline bf16x8 load_cc16(const short* p){
  const uint64_t* q = (const uint64_t*)p;
  union { uint64_t u[2]; bf16x8 v; } r;
  r.u[0] = __hip_atomic_load(q + 0, __ATOMIC_RELAXED, __HIP_MEMORY_SCOPE_AGENT);
  r.u[1] = __hip_atomic_load(q + 1, __ATOMIC_RELAXED, __HIP_MEMORY_SCOPE_AGENT);
  return r.v;
}

__global__ __launch_bounds__(TPB, 2)   // 8 waves = 2/SIMD -> VGPR cap 256
void rnn_main(const float* __restrict__ x,
              const float* __restrict__ w_ih, const float* __restrict__ b_ih,
              const float* __restrict__ w_hh, const float* __restrict__ b_hh,
              float* __restrict__ out,
              short* hring, int* tags, int useglobals)
{
  if (useglobals){ hring = g_hring_fb; tags = g_tags_fb; }
  const int tagbase = useglobals ? (g_epoch * 512) : 0;

  const int tid  = threadIdx.x;
  const int wv   = tid >> 6;             // 0..7
  const int lane = tid & 63;
  const int bid  = blockIdx.x;           // grid = NL*GM*GN = 64
  const int n = bid >> 4;                // 0..3 column group
  const int i = (bid >> 2) & 3;          // layer
  const int m = bid & 3;                 // batch group

  const int l15  = lane & 15;
  const int lq   = lane >> 4;            // quarter-wave 0..3
  const int jcol = n*128 + wv*16 + l15;  // this wave's 16 output cols
  const int ksub = lq * 8;

  // staging geometry: thread owns cols c0..c0+7 of rows r0 and r0+8
  const int r0 = tid >> 6;               // 0..7
  const int c0 = (tid & 63) * 8;         // 0..504

  // Double-buffered A tile [16 rows][1024 k] bf16, padded. 2 x 33 KB = 66 KB.
  __shared__ short lA[2][16 * LDS_STRIDE];

  // ---- persistent weight fragments: B-operand, [16 cols x 1024 k] per wave ----
  bf16x8 wf[32];
  {
    const float* wih = w_ih + (long)i*HH*HH + (long)jcol*HH;
    const float* whh = w_hh + (long)i*HH*HH + (long)jcol*HH;
    #pragma unroll
    for (int kk = 0; kk < 16; ++kk){
      const float* p = wih + kk*32 + ksub;
      f32x4 a = *(const f32x4*)p, b = *(const f32x4*)(p + 4);
      bf16x8 s;
      s[0]=f2bf(a[0]); s[1]=f2bf(a[1]); s[2]=f2bf(a[2]); s[3]=f2bf(a[3]);
      s[4]=f2bf(b[0]); s[5]=f2bf(b[1]); s[6]=f2bf(b[2]); s[7]=f2bf(b[3]);
      wf[kk] = s;
      const float* q = whh + kk*32 + ksub;
      f32x4 c = *(const f32x4*)q, d = *(const f32x4*)(q + 4);
      bf16x8 u;
      u[0]=f2bf(c[0]); u[1]=f2bf(c[1]); u[2]=f2bf(c[2]); u[3]=f2bf(c[3]);
      u[4]=f2bf(d[0]); u[5]=f2bf(d[1]); u[6]=f2bf(d[2]); u[7]=f2bf(d[3]);
      wf[kk + 16] = u;
    }
  }
  const float bsum = b_ih[(long)i*HH + jcol] + b_hh[(long)i*HH + jcol];

  float* states = out + (long)SEQ*BB*HH;   // all_states region: [(t*4+i)][b][h]
  const int bg0 = m * 16;

  for (int t = 0; t < SEQ; ++t){
    short* buf  = lA[t & 1];
    short* bufN = lA[(t + 1) & 1];

    // ---- combined readiness spin (sentinel tags only, both edges at once) ----
    {
      const int* tp; int target; bool need;
      if (lane < 32){
        tp     = tags + (i*GM + m)*32 + lane;          // self family line
        target = tagbase + t;                          // family published t-1
        need   = (t > 0) && ((lane >> 3) != n);        // own WG: barrier-synced
      } else {
        tp     = tags + ((i > 0 ? i-1 : 0)*GM + m)*32 + (lane - 32); // feed line
        target = tagbase + t + 1;                      // layer i-1 published t
        need   = (i > 0);
      }
      int it = 0;
      for (;;){
        int v = need ? __hip_atomic_load(tp, __ATOMIC_RELAXED, __HIP_MEMORY_SCOPE_AGENT)
                     : 0x7fffffff;
        if (__all(v >= target)) break;
        if (++it > (1 << 20)) break;   // bailout: wrong-but-terminating beats hang
      }
      __builtin_amdgcn_sched_barrier(0);  // pin: no data-load motion above spin
    }

    // ---- stage feed half (cols 0..511 of A) ----
    if (i == 0){
      const float* xs0 = x + ((long)t*BB + bg0 + r0    )*HH + c0;
      const float* xs1 = x + ((long)t*BB + bg0 + r0 + 8)*HH + c0;
      f32x4 a = *(const f32x4*)xs0, b = *(const f32x4*)(xs0 + 4);
      f32x4 c = *(const f32x4*)xs1, d = *(const f32x4*)(xs1 + 4);
      bf16x8 s, u;
      s[0]=f2bf(a[0]); s[1]=f2bf(a[1]); s[2]=f2bf(a[2]); s[3]=f2bf(a[3]);
      s[4]=f2bf(b[0]); s[5]=f2bf(b[1]); s[6]=f2bf(b[2]); s[7]=f2bf(b[3]);
      u[0]=f2bf(c[0]); u[1]=f2bf(c[1]); u[2]=f2bf(c[2]); u[3]=f2bf(c[3]);
      u[4]=f2bf(d[0]); u[5]=f2bf(d[1]); u[6]=f2bf(d[2]); u[7]=f2bf(d[3]);
      *(bf16x8*)(buf + r0*LDS_STRIDE + c0)     = s;
      *(bf16x8*)(buf + (r0+8)*LDS_STRIDE + c0) = u;
    } else {
      const short* fb = hring + (((long)(t & (NBUF-1)))*NL + (i-1))*(long)(BB*HH);
      bf16x8 a = load_cc16(fb + (long)(bg0 + r0    )*HH + c0);
      bf16x8 b = load_cc16(fb + (long)(bg0 + r0 + 8)*HH + c0);
      *(bf16x8*)(buf + r0*LDS_STRIDE + c0)     = a;
      *(bf16x8*)(buf + (r0+8)*LDS_STRIDE + c0) = b;
    }

    // ---- stage h half (cols 512..1023), foreign col-blocks only ----
    if (t > 0 && ((c0 >> 7) != n)){
      const short* hb = hring + (((long)((t-1) & (NBUF-1)))*NL + i)*(long)(BB*HH);
      bf16x8 a = load_cc16(hb + (long)(bg0 + r0    )*HH + c0);
      bf16x8 b = load_cc16(hb + (long)(bg0 + r0 + 8)*HH + c0);
      *(bf16x8*)(buf + r0*LDS_STRIDE + 512 + c0)     = a;
      *(bf16x8*)(buf + (r0+8)*LDS_STRIDE + 512 + c0) = b;
    }
    __syncthreads();   // the ONE barrier of the step: stage -> MFMA-read

    // ---- MFMA: out[16 rows x 16 cols]/wave, K=1024 (512 at t==0) ----
    f32x4 acc = {0.f, 0.f, 0.f, 0.f};
    const short* arow = buf + l15*LDS_STRIDE + ksub;
    #pragma unroll
    for (int kk = 0; kk < 16; ++kk)
      acc = __builtin_amdgcn_mfma_f32_16x16x32_bf16(*(const bf16x8*)(arow + kk*32), wf[kk], acc, 0, 0, 0);
    if (t > 0){
      #pragma unroll
      for (int kk = 16; kk < 32; ++kk)
        acc = __builtin_amdgcn_mfma_f32_16x16x32_bf16(*(const bf16x8*)(arow + kk*32), wf[kk], acc, 0, 0, 0);
    }

    // ---- epilogue: tanh + pack; own-column shortcut into next LDS buffer ----
    float vv[4]; short hb16[4];
    #pragma unroll
    for (int r = 0; r < 4; ++r){
      vv[r]   = fast_tanh(acc[r] + bsum);  // C/D: col=lane&15, row=lq*4+r
      hb16[r] = f2bf(vv[r]);
      if (t + 1 < SEQ)   // safe: bufN's last readers finished before THIS step's barrier
        bufN[(lq*4 + r)*LDS_STRIDE + 512 + n*128 + wv*16 + l15] = hb16[r];
    }

    // ---- act stores to ring (agent 2B, coalesced per row) ----
    {
      short* hw = hring + (((long)(t & (NBUF-1)))*NL + i)*(long)(BB*HH);
      #pragma unroll
      for (int r = 0; r < 4; ++r)
        __hip_atomic_store(hw + (long)(bg0 + lq*4 + r)*HH + jcol, hb16[r],
                           __ATOMIC_RELAXED, __HIP_MEMORY_SCOPE_AGENT);
    }

    // ---- per-wave publish: drain OWN stores, then ONE plain tag store ----
    asm volatile("s_waitcnt vmcnt(0)" ::: "memory");
    if (lane == 0)
      __hip_atomic_store(&tags[(i*GM + m)*32 + n*8 + wv], tagbase + t + 1,
                         __ATOMIC_RELAXED, __HIP_MEMORY_SCOPE_AGENT);

    // ---- deferred f32 result stores: drain in the shadow of next step ----
    #pragma unroll
    for (int r = 0; r < 4; ++r){
      long srow = (long)(t*NL + i)*BB + bg0 + lq*4 + r;
      __builtin_nontemporal_store(vv[r], states + srow*HH + jcol);
    }
    if (i == NL-1){
      #pragma unroll
      for (int r = 0; r < 4; ++r)
        __builtin_nontemporal_store(vv[r], out + ((long)t*BB + bg0 + lq*4 + r)*HH + jcol);
    }
  }
}

extern "C" void kernel_launch(void* const* d_in, const int* in_sizes, int n_in,
                              void* d_out, int out_size, void* d_ws, size_t ws_size,
                              hipStream_t stream)
{
  (void)in_sizes; (void)n_in; (void)out_size;
  const float* x    = (const float*)d_in[0];
  const float* w_ih = (const float*)d_in[1];
  const float* b_ih = (const float*)d_in[2];
  const float* w_hh = (const float*)d_in[3];
  const float* b_hh = (const float*)d_in[4];
  float* out = (float*)d_out;

  // ws layout: [0, 4MB) bf16 h ring | [4MB, +2KB) tags (poisoned 0xAA ->
  // negative ints -> self-initializing unready state; no prep pass needed).
  const size_t HR_BYTES = (size_t)NBUF*NL*BB*HH*2;   // 4 MB
  const size_t NEED     = HR_BYTES + (size_t)NTAG*4;
  int useglobals = !(d_ws != nullptr && ws_size >= NEED);

  short* hring = useglobals ? nullptr : (short*)d_ws;
  int*   tags  = useglobals ? nullptr : (int*)((char*)d_ws + HR_BYTES);

  if (useglobals)   // fallback: epoch-bump makes stale global tags unready
    hipLaunchKernelGGL(bump_epoch, dim3(1), dim3(1), 0, stream);
  hipLaunchKernelGGL(rnn_main, dim3(NL*GM*GN), dim3(TPB), 0, stream,
                     x, w_ih, b_ih, w_hh, b_hh, out, hring, tags, useglobals);
}

// Round 6
// 1075.624 us; speedup vs baseline: 1.4169x; 1.3866x over previous
//
#include <hip/hip_runtime.h>
#include <stdint.h>

// SelfRNN: 4-layer tanh RNN, SEQ=256, B=64, H=512.
// R8: consolidation on the proven R3 skeleton (best: 927us dispatch/1091 total).
// Scoreboard: R4=1035 (32 RMWs/flag), R5=1403 (spin bandwidth), R6=1372
// (512 polling waves), R7=DNF (XCD fast-path misdetection -> poll bailouts).
// Protocol lessons kept: ONE poller (tid0) per WG, everyone else at intra-CU
// barriers; WG-granular flags; agent-scope data; publish after the
// __syncthreads vmcnt(0) drain. R8 removes only non-protocol overhead:
//  (1) single dispatch: no prep kernel. Flags = per-t slots (4 dwords per
//      (t,i,m) family group, one per producer WG n), PLAIN agent stores (no
//      RMW). 0xAA ws poison = negative int = unready under signed compare
//      (mechanism proven in R6) -> no zero-init pass. Layer 0 converts
//      f32 x while staging (no feed wait -> off critical path).
//  (2) combined wait: tid0 polls feed+self groups in ONE loop -> one
//      broadcast barrier (3 barriers/step instead of 4).
//  (3) reg-staged loads: feed + h loads all issue after the combined
//      barrier -> one latency exposure instead of two serial ones.
//  (4) no inline asm. Fallback (ws too small): flags in BSS + epoch bump
//      kernel; comm via f32 states region (R3's usews==0 path).

#define SEQ 256
#define BB  64
#define HH  512
#define NL  4
#define GM  4          // batch groups of 16 rows
#define GN  4          // column groups of 128 cols (16 per wave, 8 waves)
#define TPB 512        // threads per workgroup (8 waves)
#define FSTRIDE 16     // dwords between flag groups (64B -> no false sharing)
#define LDS_STRIDE 1032  // 1024 + 8 shorts pad -> conflict-benign b128 reads
#define NFLAG (SEQ*NL*GM*FSTRIDE)

typedef __attribute__((ext_vector_type(8))) short bf16x8;
typedef __attribute__((ext_vector_type(4))) float f32x4;

// Fallback-only state (ws too small): flags live in BSS, epoch bump makes
// stale markers from previous calls/replays unready.
__device__ int g_epoch = 0;
__device__ int g_flags[NFLAG];
__global__ void bump_epoch(){ g_epoch += 1; }

__device__ inline short f2bf(float f){
  uint32_t u = __builtin_bit_cast(uint32_t, f);
  u += 0x7fffu + ((u >> 16) & 1u);   // round-to-nearest-even
  return (short)(u >> 16);
}
__device__ inline float fast_tanh(float xv){
  xv = fminf(15.0f, fmaxf(-15.0f, xv));
  float e = __expf(2.0f * xv);
  return (e - 1.0f) / (e + 1.0f);
}

// Agent-coherent 16B load (2x u64; R3-proven path for communicated bf16).
__device__ inline bf16x8 load_cc16(const short* p){
  const uint64_t* q = (const uint64_t*)p;
  union { uint64_t u[2]; bf16x8 v; } r;
  r.u[0] = __hip_atomic_load(q+0, __ATOMIC_RELAXED, __HIP_MEMORY_SCOPE_AGENT);
  r.u[1] = __hip_atomic_load(q+1, __ATOMIC_RELAXED, __HIP_MEMORY_SCOPE_AGENT);
  return r.v;
}
// Fallback: agent-coherent load of 8 f32 -> bf16x8.
__device__ inline bf16x8 load_cc_f32x8(const float* p){
  const uint64_t* q = (const uint64_t*)p;
  bf16x8 s;
  #pragma unroll
  for (int z = 0; z < 4; ++z){
    uint64_t u = __hip_atomic_load(q+z, __ATOMIC_RELAXED, __HIP_MEMORY_SCOPE_AGENT);
    s[2*z+0] = f2bf(__builtin_bit_cast(float, (uint32_t)(u & 0xffffffffu)));
    s[2*z+1] = f2bf(__builtin_bit_cast(float, (uint32_t)(u >> 32)));
  }
  return s;
}

// Check one 4-slot flag group: all slots >= thr (signed; 0xAA poison < 0).
__device__ inline bool grp_ready(const int* p, int thr){
  const uint64_t* q = (const uint64_t*)p;
  uint64_t a = __hip_atomic_load(q+0, __ATOMIC_RELAXED, __HIP_MEMORY_SCOPE_AGENT);
  uint64_t b = __hip_atomic_load(q+1, __ATOMIC_RELAXED, __HIP_MEMORY_SCOPE_AGENT);
  return ((int)a >= thr) && ((int)(a>>32) >= thr) &&
         ((int)b >= thr) && ((int)(b>>32) >= thr);
}

__global__ __launch_bounds__(TPB, 2)   // 8 waves = 2/SIMD -> VGPR cap 256
void rnn_main(const float* __restrict__ x,
              const float* __restrict__ w_ih, const float* __restrict__ b_ih,
              const float* __restrict__ w_hh, const float* __restrict__ b_hh,
              float* __restrict__ out,
              short* actbf, int* flags, int usefb)
{
  int mark = 1;
  if (usefb){ flags = g_flags; mark = g_epoch; }

  const int tid  = threadIdx.x;
  const int wv   = tid >> 6;             // 0..7
  const int lane = tid & 63;
  const int bid  = blockIdx.x;           // grid = NL*GM*GN = 64
  const int n = bid >> 4;                // 0..3 column group
  const int i = (bid >> 2) & 3;          // layer
  const int m = bid & 3;                 // batch group

  const int l15  = lane & 15;
  const int lq   = lane >> 4;            // quarter-wave 0..3
  const int jcol = n*128 + wv*16 + l15;  // this wave's 16 output cols
  const int ksub = lq * 8;

  // staging geometry: thread owns cols c0..c0+7 of rows r0 and r0+8
  const int r0 = tid >> 6;               // 0..7
  const int c0 = (tid & 63) * 8;         // 0..504

  __shared__ short lA[16 * LDS_STRIDE];  // A tile [16 rows][1024 k] bf16

  // ---- persistent weight fragments: B-operand, [16 cols x 1024 k]/wave ----
  bf16x8 wf[32];
  {
    const float* wih = w_ih + (long)i*HH*HH + (long)jcol*HH;
    const float* whh = w_hh + (long)i*HH*HH + (long)jcol*HH;
    #pragma unroll
    for (int kk = 0; kk < 16; ++kk){
      const float* p = wih + kk*32 + ksub;
      f32x4 a = *(const f32x4*)p, b = *(const f32x4*)(p + 4);
      bf16x8 s;
      s[0]=f2bf(a[0]); s[1]=f2bf(a[1]); s[2]=f2bf(a[2]); s[3]=f2bf(a[3]);
      s[4]=f2bf(b[0]); s[5]=f2bf(b[1]); s[6]=f2bf(b[2]); s[7]=f2bf(b[3]);
      wf[kk] = s;
      const float* q = whh + kk*32 + ksub;
      f32x4 c = *(const f32x4*)q, d = *(const f32x4*)(q + 4);
      bf16x8 u;
      u[0]=f2bf(c[0]); u[1]=f2bf(c[1]); u[2]=f2bf(c[2]); u[3]=f2bf(c[3]);
      u[4]=f2bf(d[0]); u[5]=f2bf(d[1]); u[6]=f2bf(d[2]); u[7]=f2bf(d[3]);
      wf[kk + 16] = u;
    }
  }
  const float bsum = b_ih[(long)i*HH + jcol] + b_hh[(long)i*HH + jcol];

  float* states = out + (long)SEQ*BB*HH;   // all_states: [(t*4+i)][b][h]
  const int bg0 = m * 16;

  for (int t = 0; t < SEQ; ++t){
    // ---- combined wait: tid0 polls feed (i-1 @ t) AND self (i @ t-1) ----
    const bool needF = (i > 0), needS = (t > 0);
    if (needF || needS){
      if (tid == 0){
        const int* pf = flags + ((t*NL + (i-1))*GM + m)*FSTRIDE;
        const int* ps = flags + (((t-1)*NL + i)*GM + m)*FSTRIDE;
        bool okF = !needF, okS = !needS;
        int it = 0;
        for (;;){
          if (!okF) okF = grp_ready(pf, mark);
          if (!okS) okS = grp_ready(ps, mark);
          if (okF && okS) break;
          __builtin_amdgcn_s_sleep(1);
          if (++it > (1 << 24)) break;  // bailout: terminating beats hang
        }
      }
      __syncthreads();   // broadcast readiness (also orders later loads)
    }

    // ---- issue all communicated loads into registers (one exposure) ----
    bf16x8 f0, f1, h0, h1;
    if (i == 0){
      const float* xs0 = x + ((long)t*BB + bg0 + r0    )*HH + c0;
      const float* xs1 = x + ((long)t*BB + bg0 + r0 + 8)*HH + c0;
      f32x4 a = *(const f32x4*)xs0, b = *(const f32x4*)(xs0 + 4);
      f32x4 c = *(const f32x4*)xs1, d = *(const f32x4*)(xs1 + 4);
      f0[0]=f2bf(a[0]); f0[1]=f2bf(a[1]); f0[2]=f2bf(a[2]); f0[3]=f2bf(a[3]);
      f0[4]=f2bf(b[0]); f0[5]=f2bf(b[1]); f0[6]=f2bf(b[2]); f0[7]=f2bf(b[3]);
      f1[0]=f2bf(c[0]); f1[1]=f2bf(c[1]); f1[2]=f2bf(c[2]); f1[3]=f2bf(c[3]);
      f1[4]=f2bf(d[0]); f1[5]=f2bf(d[1]); f1[6]=f2bf(d[2]); f1[7]=f2bf(d[3]);
    } else if (!usefb){
      const short* fb = actbf + ((size_t)(t*NL + (i-1))*BB)*HH;
      f0 = load_cc16(fb + (size_t)(bg0 + r0    )*HH + c0);
      f1 = load_cc16(fb + (size_t)(bg0 + r0 + 8)*HH + c0);
    } else {
      const float* fb = states + ((long)(t*NL + (i-1))*BB)*HH;
      f0 = load_cc_f32x8(fb + (long)(bg0 + r0    )*HH + c0);
      f1 = load_cc_f32x8(fb + (long)(bg0 + r0 + 8)*HH + c0);
    }
    if (t > 0){
      if (!usefb){
        const short* hb = actbf + ((size_t)((t-1)*NL + i)*BB)*HH;
        h0 = load_cc16(hb + (size_t)(bg0 + r0    )*HH + c0);
        h1 = load_cc16(hb + (size_t)(bg0 + r0 + 8)*HH + c0);
      } else {
        const float* hb = states + ((long)((t-1)*NL + i)*BB)*HH;
        h0 = load_cc_f32x8(hb + (long)(bg0 + r0    )*HH + c0);
        h1 = load_cc_f32x8(hb + (long)(bg0 + r0 + 8)*HH + c0);
      }
    }

    // ---- stage to LDS, then the stage->MFMA barrier ----
    *(bf16x8*)(lA + r0*LDS_STRIDE + c0)     = f0;
    *(bf16x8*)(lA + (r0+8)*LDS_STRIDE + c0) = f1;
    if (t > 0){
      *(bf16x8*)(lA + r0*LDS_STRIDE + 512 + c0)     = h0;
      *(bf16x8*)(lA + (r0+8)*LDS_STRIDE + 512 + c0) = h1;
    }
    __syncthreads();

    // ---- MFMA: out[16 rows x 16 cols]/wave, K=1024 (512 at t==0) ----
    f32x4 acc = {0.f, 0.f, 0.f, 0.f};
    const short* arow = lA + l15*LDS_STRIDE + ksub;
    #pragma unroll
    for (int kk = 0; kk < 16; ++kk)
      acc = __builtin_amdgcn_mfma_f32_16x16x32_bf16(*(const bf16x8*)(arow + kk*32), wf[kk], acc, 0, 0, 0);
    if (t > 0){
      #pragma unroll
      for (int kk = 16; kk < 32; ++kk)
        acc = __builtin_amdgcn_mfma_f32_16x16x32_bf16(*(const bf16x8*)(arow + kk*32), wf[kk], acc, 0, 0, 0);
    }

    // ---- epilogue: bias + tanh; communicated stores (agent scope) ----
    float vv[4]; short hb16[4];
    #pragma unroll
    for (int r = 0; r < 4; ++r){
      vv[r]   = fast_tanh(acc[r] + bsum);  // C/D: col=lane&15, row=lq*4+r
      hb16[r] = f2bf(vv[r]);
    }
    if (!usefb){
      short* aw = actbf + ((size_t)(t*NL + i)*BB)*HH;
      #pragma unroll
      for (int r = 0; r < 4; ++r)
        __hip_atomic_store(aw + (size_t)(bg0 + lq*4 + r)*HH + jcol, hb16[r],
                           __ATOMIC_RELAXED, __HIP_MEMORY_SCOPE_AGENT);
    } else {
      #pragma unroll
      for (int r = 0; r < 4; ++r){
        long srow = (long)(t*NL + i)*BB + bg0 + lq*4 + r;
        __hip_atomic_store((uint32_t*)(states + srow*HH + jcol),
                           __builtin_bit_cast(uint32_t, vv[r]),
                           __ATOMIC_RELAXED, __HIP_MEMORY_SCOPE_AGENT);
      }
    }

    // ---- drain + publish: __syncthreads emits vmcnt(0) before s_barrier,
    //      so every wave's agent stores reached the coherence point; then
    //      tid0's PLAIN flag store (no RMW) publishes for both consumers ----
    __syncthreads();
    if (tid == 0)
      __hip_atomic_store(&flags[((t*NL + i)*GM + m)*FSTRIDE + n], mark,
                         __ATOMIC_RELAXED, __HIP_MEMORY_SCOPE_AGENT);

    // ---- deferred f32 result stores: drain in the shadow of next step ----
    if (!usefb){
      #pragma unroll
      for (int r = 0; r < 4; ++r){
        long srow = (long)(t*NL + i)*BB + bg0 + lq*4 + r;
        __builtin_nontemporal_store(vv[r], states + srow*HH + jcol);
      }
    }
    if (i == NL-1){
      #pragma unroll
      for (int r = 0; r < 4; ++r)
        __builtin_nontemporal_store(vv[r], out + ((long)t*BB + bg0 + lq*4 + r)*HH + jcol);
    }
  }
}

extern "C" void kernel_launch(void* const* d_in, const int* in_sizes, int n_in,
                              void* d_out, int out_size, void* d_ws, size_t ws_size,
                              hipStream_t stream)
{
  (void)in_sizes; (void)n_in; (void)out_size;
  const float* x    = (const float*)d_in[0];
  const float* w_ih = (const float*)d_in[1];
  const float* b_ih = (const float*)d_in[2];
  const float* w_hh = (const float*)d_in[3];
  const float* b_hh = (const float*)d_in[4];
  float* out = (float*)d_out;

  // ws layout: [0, 256K) flags [SEQ][NL][GM][16 dwords] (0xAA poison =
  // negative = unready; no init pass) | [256K, +64M) actbf bf16 feed/self
  // payload [SEQ*NL][BB][HH].
  const size_t FLAG_BYTES = (size_t)NFLAG*4;                 // 256 KB
  const size_t ACT_OFF    = FLAG_BYTES;
  const size_t NEED       = ACT_OFF + (size_t)SEQ*NL*BB*HH*2; // ~67 MB
  int usefb = !(d_ws != nullptr && ws_size >= NEED);

  int*   flags = usefb ? nullptr : (int*)d_ws;
  short* actbf = usefb ? nullptr : (short*)((char*)d_ws + ACT_OFF);

  if (usefb)   // fallback: epoch bump invalidates stale BSS flag markers
    hipLaunchKernelGGL(bump_epoch, dim3(1), dim3(1), 0, stream);
  hipLaunchKernelGGL(rnn_main, dim3(NL*GM*GN), dim3(TPB), 0, stream,
                     x, w_ih, b_ih, w_hh, b_hh, out, actbf, flags, usefb);
}